// Round 3
// baseline (286.095 us; speedup 1.0000x reference)
//
#include <hip/hip_runtime.h>
#include <hip/hip_bf16.h>

// Dims fixed by the reference
#define BB 8
#define NN 2048
#define DF 256
#define HH 64

using bf16x8 = __attribute__((ext_vector_type(8))) short;
using f32x4  = __attribute__((ext_vector_type(4))) float;
typedef unsigned short u16;

// ---------------------------------------------------------------------------
// Kernel 1: Q/K projection. q = [f | log_eps] @ W_q (scale 1/8 folded into q),
// k likewise. Output split bf16 (hi, lo): [bn][ hi(0..63) | lo(0..63) ].
// v3: 16 rows/block (1024 blocks -> 4 waves/SIMD) for latency hiding; W chunks
// in LDS (conflict-free), f via wave-uniform broadcast loads (no LDS pipe use).
// ---------------------------------------------------------------------------
__global__ __launch_bounds__(256) void qk_proj_kernel(
    const float* __restrict__ f, const float* __restrict__ log_eps,
    const float* __restrict__ Wq, const float* __restrict__ Wk,
    __hip_bfloat16* __restrict__ Qs, __hip_bfloat16* __restrict__ Ks)
{
    __shared__ float wql[64 * 64];           // W_q chunk: [i_local][h]
    __shared__ float wkl[64 * 64];           // W_k chunk
    const int tid = threadIdx.x;
    const int h  = tid & 63;                 // head dim (lane)
    const int rg = tid >> 6;                 // wave id -> row group (4 rows)
    const int row_base = blockIdx.x * 16;    // flat bn of first row
    const int b = row_base >> 11;            // blocks never straddle batches

    const float le = log_eps[b];
    const float wq_last = Wq[DF * HH + h];
    const float wk_last = Wk[DF * HH + h];
    float q[4], k[4];
#pragma unroll
    for (int j = 0; j < 4; ++j) { q[j] = le * wq_last; k[j] = le * wk_last; }

    for (int kc = 0; kc < 4; ++kc) {
        __syncthreads();                     // LDS reuse guard
#pragma unroll
        for (int it = 0; it < 4; ++it) {
            int idx = (tid + it * 256) * 4;  // float offset, 0..4095
            *(float4*)&wql[idx] = *(const float4*)(Wq + kc * 4096 + idx);
            *(float4*)&wkl[idx] = *(const float4*)(Wk + kc * 4096 + idx);
        }
        __syncthreads();

        const float* fb = f + (size_t)(row_base + rg * 4) * DF + kc * 64;
#pragma unroll 8
        for (int i4 = 0; i4 < 16; ++i4) {
            float4 fv[4];                    // wave-uniform broadcast loads
#pragma unroll
            for (int j = 0; j < 4; ++j)
                fv[j] = *(const float4*)(fb + (size_t)j * DF + i4 * 4);
#pragma unroll
            for (int u = 0; u < 4; ++u) {
                float wq = wql[(i4 * 4 + u) * 64 + h];
                float wk = wkl[(i4 * 4 + u) * 64 + h];
#pragma unroll
                for (int j = 0; j < 4; ++j) {
                    float fvv = (&fv[j].x)[u];
                    q[j] = fmaf(fvv, wq, q[j]);
                    k[j] = fmaf(fvv, wk, k[j]);
                }
            }
        }
    }

#pragma unroll
    for (int j = 0; j < 4; ++j) {
        int bn = row_base + rg * 4 + j;
        float qv = q[j] * 0.125f;            // 1/sqrt(64) folded into q
        float kv = k[j];
        __hip_bfloat16 qh = __float2bfloat16(qv);
        __hip_bfloat16 ql = __float2bfloat16(qv - __bfloat162float(qh));
        __hip_bfloat16 kh = __float2bfloat16(kv);
        __hip_bfloat16 kl = __float2bfloat16(kv - __bfloat162float(kh));
        size_t base = (size_t)bn * 128;
        Qs[base + h]      = qh;
        Qs[base + 64 + h] = ql;
        Ks[base + h]      = kh;
        Ks[base + 64 + h] = kl;
    }
}

// ---------------------------------------------------------------------------
// Kernel 2 (colsum): block = 32-col strip x 256-row tile. Computes
// sum_n exp(q_n . k_m) for its rows, accumulates into global cs[b][m] via
// one atomicAdd per column. Grid 4096 -> 16 blocks/CU queued (full hiding).
// MFMA layout: A=Q rows, B=K cols; D col=lane&15 (K), row=quad*4+reg (Q).
// ---------------------------------------------------------------------------
__global__ __launch_bounds__(256) void colsum_kernel(
    const u16* __restrict__ Qs, const u16* __restrict__ Ks,
    float* __restrict__ cs)
{
    __shared__ float cs_lds[32];
    const int tid  = threadIdx.x;
    const int m0   = blockIdx.x * 32;
    const int rt   = blockIdx.y;             // 0..7 (256-row tile)
    const int b    = blockIdx.z;
    const int wave = tid >> 6;
    const int lane = tid & 63;
    const int l15  = lane & 15;
    const int quad = lane >> 4;

    if (tid < 32) cs_lds[tid] = 0.f;
    __syncthreads();

    // K fragments resident: B[n=lane&15][k=quad*8+j]
    bf16x8 bh[2][2], bl[2][2];
    {
        const u16* Kb = Ks + ((size_t)b * NN + m0) * 128;
#pragma unroll
        for (int ct = 0; ct < 2; ++ct) {
            const u16* kr = Kb + (size_t)(ct * 16 + l15) * 128;
#pragma unroll
            for (int ks = 0; ks < 2; ++ks) {
                int k0 = ks * 32 + quad * 8;
                bh[ct][ks] = *(const bf16x8*)(kr + k0);
                bl[ct][ks] = *(const bf16x8*)(kr + 64 + k0);
            }
        }
    }

    const u16* Qb = Qs + (size_t)b * NN * 128;
    float cs0 = 0.f, cs1 = 0.f;
#pragma unroll
    for (int sr = 0; sr < 4; ++sr) {
        const int row0 = rt * 256 + wave * 64 + sr * 16;
        const u16* qr = Qb + (size_t)(row0 + l15) * 128;
        bf16x8 ah[2], al[2];
#pragma unroll
        for (int ks = 0; ks < 2; ++ks) {
            int k0 = ks * 32 + quad * 8;
            ah[ks] = *(const bf16x8*)(qr + k0);
            al[ks] = *(const bf16x8*)(qr + 64 + k0);
        }
#pragma unroll
        for (int ct = 0; ct < 2; ++ct) {
            f32x4 acc = {0.f, 0.f, 0.f, 0.f};
#pragma unroll
            for (int ks = 0; ks < 2; ++ks) {
                acc = __builtin_amdgcn_mfma_f32_16x16x32_bf16(ah[ks], bh[ct][ks], acc, 0, 0, 0);
                acc = __builtin_amdgcn_mfma_f32_16x16x32_bf16(ah[ks], bl[ct][ks], acc, 0, 0, 0);
                acc = __builtin_amdgcn_mfma_f32_16x16x32_bf16(al[ks], bh[ct][ks], acc, 0, 0, 0);
            }
            float s = __expf(acc[0]) + __expf(acc[1]) + __expf(acc[2]) + __expf(acc[3]);
            s += __shfl_xor(s, 16);          // reduce over quads (rows)
            s += __shfl_xor(s, 32);
            if (ct == 0) cs0 += s; else cs1 += s;
        }
    }
    if (quad == 0) {
        atomicAdd(&cs_lds[l15],      cs0);
        atomicAdd(&cs_lds[16 + l15], cs1);
    }
    __syncthreads();
    if (tid < 32) atomicAdd(&cs[(size_t)b * NN + m0 + tid], cs_lds[tid]);
}

// ---------------------------------------------------------------------------
// Kernel 3 (pi + y): same tiling as colsum, but MFMA operands SWAPPED
// (A=K strip, B=Q rows) so D row=quad*4+reg spans 4 CONSECUTIVE pi columns
// -> float4 pi stores. pi[n][m] = exp * ivN[m]; y partials accumulated in
// registers over n, shuffle+LDS reduced, one atomicAdd per (m,d).
// ---------------------------------------------------------------------------
__global__ __launch_bounds__(256) void pi_y_kernel(
    const u16* __restrict__ Qs, const u16* __restrict__ Ks,
    const float* __restrict__ x, const float* __restrict__ cs,
    float* __restrict__ y, float* __restrict__ pi)
{
    __shared__ float xt[256 * 3];            // x rows for this tile
    __shared__ float iv_lds[32], ivn_lds[32];
    __shared__ float yred[4][32][3];

    const int tid  = threadIdx.x;
    const int m0   = blockIdx.x * 32;
    const int rt   = blockIdx.y;
    const int b    = blockIdx.z;
    const int n0   = rt * 256;
    const int wave = tid >> 6;
    const int lane = tid & 63;
    const int l15  = lane & 15;
    const int quad = lane >> 4;

    for (int i = tid; i < 256 * 3; i += 256) xt[i] = x[((size_t)b * NN + n0) * 3 + i];
    if (tid < 32) {
        float iv = 1.0f / cs[(size_t)b * NN + m0 + tid];
        iv_lds[tid]  = iv;
        ivn_lds[tid] = iv * (1.0f / (float)NN);
    }
    __syncthreads();

    // K fragments resident as the A operand: A[m=lane&15][k=quad*8+j]
    bf16x8 kh[2][2], kl[2][2];
    {
        const u16* Kb = Ks + ((size_t)b * NN + m0) * 128;
#pragma unroll
        for (int ct = 0; ct < 2; ++ct) {
            const u16* kr = Kb + (size_t)(ct * 16 + l15) * 128;
#pragma unroll
            for (int ks = 0; ks < 2; ++ks) {
                int k0 = ks * 32 + quad * 8;
                kh[ct][ks] = *(const bf16x8*)(kr + k0);
                kl[ct][ks] = *(const bf16x8*)(kr + 64 + k0);
            }
        }
    }

    const u16* Qb = Qs + (size_t)b * NN * 128;
    float yacc[2][4][3];
#pragma unroll
    for (int ct = 0; ct < 2; ++ct)
#pragma unroll
        for (int r = 0; r < 4; ++r)
#pragma unroll
            for (int d = 0; d < 3; ++d) yacc[ct][r][d] = 0.f;

#pragma unroll
    for (int sr = 0; sr < 4; ++sr) {
        const int nloc = wave * 64 + sr * 16 + l15;   // this lane's pi row (local)
        const u16* qr = Qb + (size_t)(n0 + nloc) * 128;
        bf16x8 qh[2], ql[2];
#pragma unroll
        for (int ks = 0; ks < 2; ++ks) {
            int k0 = ks * 32 + quad * 8;
            qh[ks] = *(const bf16x8*)(qr + k0);
            ql[ks] = *(const bf16x8*)(qr + 64 + k0);
        }
        const float xv0 = xt[nloc * 3 + 0];
        const float xv1 = xt[nloc * 3 + 1];
        const float xv2 = xt[nloc * 3 + 2];
#pragma unroll
        for (int ct = 0; ct < 2; ++ct) {
            f32x4 acc = {0.f, 0.f, 0.f, 0.f};
#pragma unroll
            for (int ks = 0; ks < 2; ++ks) {
                acc = __builtin_amdgcn_mfma_f32_16x16x32_bf16(kh[ct][ks], qh[ks], acc, 0, 0, 0);
                acc = __builtin_amdgcn_mfma_f32_16x16x32_bf16(kh[ct][ks], ql[ks], acc, 0, 0, 0);
                acc = __builtin_amdgcn_mfma_f32_16x16x32_bf16(kl[ct][ks], qh[ks], acc, 0, 0, 0);
            }
            const int mloc = ct * 16 + quad * 4;      // first of 4 consecutive cols
            f32x4 pv;
#pragma unroll
            for (int r = 0; r < 4; ++r) {
                float e = __expf(acc[r]);
                pv[r] = e * ivn_lds[mloc + r];
                yacc[ct][r][0] = fmaf(e, xv0, yacc[ct][r][0]);
                yacc[ct][r][1] = fmaf(e, xv1, yacc[ct][r][1]);
                yacc[ct][r][2] = fmaf(e, xv2, yacc[ct][r][2]);
            }
            *(f32x4*)(pi + ((size_t)b * NN + n0 + nloc) * NN + m0 + mloc) = pv;
        }
    }

    // reduce y over the 16 l15 lanes (different n rows), then across waves
#pragma unroll
    for (int ct = 0; ct < 2; ++ct)
#pragma unroll
        for (int r = 0; r < 4; ++r)
#pragma unroll
            for (int d = 0; d < 3; ++d) {
                float v = yacc[ct][r][d];
                v += __shfl_xor(v, 1);
                v += __shfl_xor(v, 2);
                v += __shfl_xor(v, 4);
                v += __shfl_xor(v, 8);
                yacc[ct][r][d] = v;
            }
    if (l15 == 0) {
#pragma unroll
        for (int ct = 0; ct < 2; ++ct)
#pragma unroll
            for (int r = 0; r < 4; ++r)
#pragma unroll
                for (int d = 0; d < 3; ++d)
                    yred[wave][ct * 16 + quad * 4 + r][d] = yacc[ct][r][d];
    }
    __syncthreads();
    if (tid < 96) {                          // 32 cols x 3 dims
        int c = tid / 3, d = tid - c * 3;
        float s = yred[0][c][d] + yred[1][c][d] + yred[2][c][d] + yred[3][c][d];
        atomicAdd(&y[((size_t)b * NN + m0 + c) * 3 + d], s * iv_lds[c]);
    }
}

// ---------------------------------------------------------------------------
extern "C" void kernel_launch(void* const* d_in, const int* in_sizes, int n_in,
                              void* d_out, int out_size, void* d_ws, size_t ws_size,
                              hipStream_t stream) {
    const float* f  = (const float*)d_in[0];
    const float* x  = (const float*)d_in[1];
    const float* le = (const float*)d_in[2];
    const float* Wq = (const float*)d_in[3];
    const float* Wk = (const float*)d_in[4];

    float* y  = (float*)d_out;                       // (B, N, 3)
    float* pi = (float*)d_out + (size_t)BB * NN * 3; // (B, N, N)

    __hip_bfloat16* Qs = (__hip_bfloat16*)d_ws;      // split-bf16 Q, K (4 MB each)
    __hip_bfloat16* Ks = Qs + (size_t)BB * NN * 128;
    float* cs = (float*)((char*)d_ws + 16u * 1024 * 1024);  // colsums (64 KB)

    hipMemsetAsync(cs, 0, (size_t)BB * NN * sizeof(float), stream);
    hipMemsetAsync(y,  0, (size_t)BB * NN * 3 * sizeof(float), stream);

    qk_proj_kernel<<<dim3(BB * NN / 16), 256, 0, stream>>>(f, le, Wq, Wk, Qs, Ks);
    colsum_kernel<<<dim3(64, 8, BB), 256, 0, stream>>>((const u16*)Qs, (const u16*)Ks, cs);
    pi_y_kernel<<<dim3(64, 8, BB), 256, 0, stream>>>((const u16*)Qs, (const u16*)Ks, x, cs, y, pi);
}